// Round 1
// 181.942 us; speedup vs baseline: 1.0319x; 1.0319x over previous
//
#include <hip/hip_runtime.h>
#include <hip/hip_bf16.h>

typedef __hip_bfloat16 bf16;
typedef _Float16 f16;
typedef __attribute__((ext_vector_type(8))) short bf16x8;
typedef __attribute__((ext_vector_type(8))) _Float16 f16x8;
typedef __attribute__((ext_vector_type(2))) _Float16 f16x2;
typedef __attribute__((ext_vector_type(4))) float f32x4;
typedef __attribute__((ext_vector_type(4))) unsigned int u32x4;
typedef __attribute__((ext_vector_type(2))) unsigned int u32x2;

#define B_ 4
#define N_ 4096
#define C_ 256
#define H_ 4
#define D_ 64
#define KLN 0.18033688011112042f   /* 0.125 * log2(e): folded into Q */

#if __has_builtin(__builtin_amdgcn_exp2f)
#define EXP2(x) __builtin_amdgcn_exp2f(x)
#else
#define EXP2(x) exp2f(x)
#endif
#if __has_builtin(__builtin_amdgcn_rcpf)
#define RCP(x) __builtin_amdgcn_rcpf(x)
#else
#define RCP(x) (1.0f / (x))
#endif

// direct global->LDS DMA, 16B per lane. LDS dest = wave-uniform base + lane*16.
__device__ inline void load_lds16(const void* g, void* l) {
#if __has_builtin(__builtin_amdgcn_global_load_lds)
    __builtin_amdgcn_global_load_lds(
        (const __attribute__((address_space(1))) unsigned int*)g,
        (__attribute__((address_space(3))) unsigned int*)l, 16, 0, 0);
#else
    int ln = __lane_id();
    ((u32x4*)l)[ln] = *((const u32x4*)g);   // fallback (not used on gfx950)
#endif
}

// two fp32 -> packed bf16 pair (round-half-up)
__device__ inline unsigned int pk2(float a, float b) {
    unsigned int ua = __builtin_bit_cast(unsigned int, a) + 0x8000u;
    unsigned int ub = __builtin_bit_cast(unsigned int, b) + 0x8000u;
    return (ua >> 16) | (ub & 0xffff0000u);
}
// two fp32 -> packed f16 pair (single v_cvt_pkrtz_f16_f32)
__device__ inline unsigned int pkh2(float a, float b) {
#if __has_builtin(__builtin_amdgcn_cvt_pkrtz)
    return __builtin_bit_cast(unsigned int, __builtin_amdgcn_cvt_pkrtz(a, b));
#else
    f16x2 h = { (f16)a, (f16)b };
    return __builtin_bit_cast(unsigned int, h);
#endif
}
__device__ inline short f2s(float x) {
    return (short)__builtin_bit_cast(unsigned short, __float2bfloat16(x));
}
__device__ inline bf16x8 cvt8(const float* __restrict__ p) {
    f32x4 a = *reinterpret_cast<const f32x4*>(p);
    f32x4 b = *reinterpret_cast<const f32x4*>(p + 4);
    bf16x8 r = { f2s(a[0]), f2s(a[1]), f2s(a[2]), f2s(a[3]),
                 f2s(b[0]), f2s(b[1]), f2s(b[2]), f2s(b[3]) };
    return r;
}

// ---------------------------------------------------------------------------
// Prep: cast x, w_qkv, w_proj fp32 -> bf16 (memory-bound).
// ---------------------------------------------------------------------------
__global__ __launch_bounds__(256) void cast_bf16(const float* __restrict__ x,
                                                 const float* __restrict__ wq,
                                                 const float* __restrict__ wp,
                                                 bf16* __restrict__ xb,
                                                 bf16* __restrict__ wqb,
                                                 bf16* __restrict__ wpb)
{
    int bid = blockIdx.x;
    const float* s; bf16* d; int base;
    if (bid < 2048)      { s = x;  d = xb;  base = bid * 2048; }
    else if (bid < 2144) { s = wq; d = wqb; base = (bid - 2048) * 2048; }
    else                 { s = wp; d = wpb; base = (bid - 2144) * 2048; }
    int i = base + threadIdx.x * 8;
    f32x4 a = *reinterpret_cast<const f32x4*>(s + i);
    f32x4 b = *reinterpret_cast<const f32x4*>(s + i + 4);
    u32x4 o;
    o.x = pk2(a[0], a[1]); o.y = pk2(a[2], a[3]);
    o.z = pk2(b[0], b[1]); o.w = pk2(b[2], b[3]);
    *reinterpret_cast<u32x4*>(d + i) = o;
}

// ---------------------------------------------------------------------------
// QKV projection, W staged in LDS. Q pre-scaled by KLN; V -> [B,H,D,N] f16.
// For Q/K the MFMA operands are SWAPPED (A/B fragments share the same lane
// layout) so the accumulator is transposed: each lane then holds 4 contiguous
// d-values of one row -> 4x u32x2 stores instead of 16 scalar bf16 stores.
// XCD swizzle groups the 12 n-tiles of each x-tile on one XCD (L2 reuse).
// ---------------------------------------------------------------------------
__global__ __launch_bounds__(256, 2) void qkv_fast(const bf16* __restrict__ x,
                                                   const bf16* __restrict__ w,
                                                   bf16* __restrict__ qw,
                                                   bf16* __restrict__ kw,
                                                   f16* __restrict__ vtw)
{
    __shared__ short w_s[64][264];
    const int tid  = threadIdx.x;
    const int lane = tid & 63;
    const int wav  = tid >> 6;
    const int quad = lane >> 4;
    const int l16  = lane & 15;
    const int bid = (blockIdx.x & 7) * 384 + (blockIdx.x >> 3);   // 3072 = 8*384
    const int mt = bid / 12, nb = bid % 12;
    const int m0 = mt * 64, n0 = nb * 64;

    {
        const int row = tid >> 2, cb = (tid & 3) * 64;
        const bf16* src = w + (size_t)(n0 + row) * C_ + cb;
#pragma unroll
        for (int i = 0; i < 8; ++i)
            *reinterpret_cast<bf16x8*>(&w_s[row][cb + i * 8]) =
                *reinterpret_cast<const bf16x8*>(src + i * 8);
    }
    __syncthreads();

    f32x4 acc[4] = {{0,0,0,0},{0,0,0,0},{0,0,0,0},{0,0,0,0}};
    const bf16* xrow = x + (size_t)(m0 + wav * 16 + l16) * C_ + quad * 8;
    if (nb < 8) {        // Q/K: transposed accumulator (swapped operands)
#pragma unroll
        for (int k0 = 0; k0 < C_; k0 += 32) {
            bf16x8 a = *reinterpret_cast<const bf16x8*>(xrow + k0);
#pragma unroll
            for (int nt = 0; nt < 4; ++nt) {
                bf16x8 b = *reinterpret_cast<const bf16x8*>(&w_s[nt * 16 + l16][k0 + quad * 8]);
                acc[nt] = __builtin_amdgcn_mfma_f32_16x16x32_bf16(b, a, acc[nt], 0, 0, 0);
            }
        }
    } else {             // V: normal orientation (store wants n-contiguous)
#pragma unroll
        for (int k0 = 0; k0 < C_; k0 += 32) {
            bf16x8 a = *reinterpret_cast<const bf16x8*>(xrow + k0);
#pragma unroll
            for (int nt = 0; nt < 4; ++nt) {
                bf16x8 b = *reinterpret_cast<const bf16x8*>(&w_s[nt * 16 + l16][k0 + quad * 8]);
                acc[nt] = __builtin_amdgcn_mfma_f32_16x16x32_bf16(a, b, acc[nt], 0, 0, 0);
            }
        }
    }

    const int bb = m0 >> 12;
    const int nbase = (m0 + wav * 16) & (N_ - 1);
    if (nb < 4) {                            // Q (scaled): row n = nbase+l16
        bf16* dst = qw + (((size_t)bb * H_ + nb) * N_ + nbase + l16) * D_;
#pragma unroll
        for (int nt = 0; nt < 4; ++nt) {
            u32x2 wv = { pk2(acc[nt][0] * KLN, acc[nt][1] * KLN),
                         pk2(acc[nt][2] * KLN, acc[nt][3] * KLN) };
            *reinterpret_cast<u32x2*>(dst + nt * 16 + quad * 4) = wv;
        }
    } else if (nb < 8) {                     // K
        bf16* dst = kw + (((size_t)bb * H_ + (nb - 4)) * N_ + nbase + l16) * D_;
#pragma unroll
        for (int nt = 0; nt < 4; ++nt) {
            u32x2 wv = { pk2(acc[nt][0], acc[nt][1]),
                         pk2(acc[nt][2], acc[nt][3]) };
            *reinterpret_cast<u32x2*>(dst + nt * 16 + quad * 4) = wv;
        }
    } else {                                 // V transposed, f16
        const int h = nb - 8;
#pragma unroll
        for (int nt = 0; nt < 4; ++nt) {
            int d = nt * 16 + l16;
            u32x2 wv;
            wv.x = pkh2(acc[nt][0], acc[nt][1]);
            wv.y = pkh2(acc[nt][2], acc[nt][3]);
            *reinterpret_cast<u32x2*>(
                vtw + (((size_t)bb * H_ + h) * D_ + d) * N_ + nbase + quad * 4) = wv;
        }
    }
}

// Fallback: fp32 in, cvt per fragment.
__global__ __launch_bounds__(256) void qkv_cvt(const float* __restrict__ x,
                                               const float* __restrict__ w,
                                               bf16* __restrict__ qw,
                                               bf16* __restrict__ kw,
                                               f16* __restrict__ vtw)
{
    const int lane = threadIdx.x & 63;
    const int wav  = threadIdx.x >> 6;
    const int quad = lane >> 4;
    const int l16  = lane & 15;
    const int gw   = blockIdx.x * 4 + wav;
    const int m0   = (gw / 12) * 16;
    const int n0   = (gw % 12) * 64;

    f32x4 acc[4] = {{0,0,0,0},{0,0,0,0},{0,0,0,0},{0,0,0,0}};
    const float* xrow = x + (size_t)(m0 + l16) * C_ + quad * 8;
#pragma unroll
    for (int k0 = 0; k0 < C_; k0 += 32) {
        bf16x8 a = cvt8(xrow + k0);
#pragma unroll
        for (int nt = 0; nt < 4; ++nt) {
            bf16x8 b = cvt8(w + (size_t)(n0 + nt * 16 + l16) * C_ + k0 + quad * 8);
            acc[nt] = __builtin_amdgcn_mfma_f32_16x16x32_bf16(a, b, acc[nt], 0, 0, 0);
        }
    }
#pragma unroll
    for (int nt = 0; nt < 4; ++nt)
#pragma unroll
        for (int r = 0; r < 4; ++r) {
            int m  = m0 + quad * 4 + r;
            int o  = n0 + nt * 16 + l16;
            int bb = m >> 12;
            int n  = m & (N_ - 1);
            if (o < 256) {
                int h = o >> 6, d = o & 63;
                qw[(((size_t)bb * H_ + h) * N_ + n) * D_ + d] =
                    __float2bfloat16(acc[nt][r] * KLN);
            } else if (o < 512) {
                int oo = o - 256; int h = oo >> 6, d = oo & 63;
                kw[(((size_t)bb * H_ + h) * N_ + n) * D_ + d] =
                    __float2bfloat16(acc[nt][r]);
            } else {
                int oo = o - 512; int h = oo >> 6, d = oo & 63;
                vtw[(((size_t)bb * H_ + h) * D_ + d) * N_ + n] = (f16)acc[nt][r];
            }
        }
}

// ---------------------------------------------------------------------------
// Flash attention v5. 512-thread blocks = 8 waves = 4 q-subtiles (32 rows,
// 2 MFMA q-groups each) x 2 j-halves; grid 512 = exactly 2 blocks/CU.
//
// Key change vs v4: K rows are staged under a bit-shuffle permutation
//   pi(rho): bits {b5,b4,b3,b2,b1,b0} -> {b5,b3,b2,b4,b1,b0}
// chosen so the S^T = K.Q^T output slot (nt, quad, r) holds exactly
// j = 32*(nt>>1) + 8*quad + 4*(nt&1) + r — i.e. the PV B-fragment's natural
// k-slot -> j mapping (32ks + 8quad + e), which is also V's LDS order.
// P therefore never touches LDS: exp2 -> v_cvt_pkrtz -> MFMA B-operand in
// registers. p_s (36 KB + all its bank-conflicted traffic) is deleted.
// K/V are double-buffered (64 KB LDS) with ONE barrier per tile: the DMA for
// tile t+1 is issued before computing tile t and drained by the barrier's
// implicit vmcnt(0), having had the whole compute phase to land.
// XCD swizzle: each XCD's L2 serves 2 (b,h) pairs -> 2 MB K/V working set.
// ---------------------------------------------------------------------------
__global__ __launch_bounds__(512, 4) void attn(const bf16* __restrict__ q,
                                               const bf16* __restrict__ k,
                                               const f16* __restrict__ vt,
                                               bf16* __restrict__ o)
{
    __shared__ __align__(16) char smem[65536];
    short* k_s = reinterpret_cast<short*>(smem);            // [buf][jh][64*64]
    f16*   v_s = reinterpret_cast<f16*>(smem + 32768);      // [buf][jh][64*64]

    const int tid  = threadIdx.x;
    const int lane = tid & 63;
    const int wav  = tid >> 6;       // 0..7
    const int quad = lane >> 4;
    const int l16  = lane & 15;
    const int l8   = lane & 7;
    const int sub  = wav & 3;        // 32-row q-slice within the 128-row tile
    const int jh   = wav >> 2;       // j-half

    const int wg = (blockIdx.x & 7) * 64 + (blockIdx.x >> 3);  // XCD swizzle
    const int bh = wg >> 5;
    const int qt = wg & 31;
    const int bb = bh >> 2, h = bh & 3;

    const bf16* qp = q  + (size_t)bh * N_ * D_;
    const bf16* kp = k  + (size_t)bh * N_ * D_;
    const f16*  vp = vt + (size_t)bh * D_ * N_;

    const int qbase = qt * 128 + sub * 32;
    bf16x8 qb[2][2];
#pragma unroll
    for (int qg = 0; qg < 2; ++qg)
#pragma unroll
        for (int ks = 0; ks < 2; ++ks)
            qb[qg][ks] = *reinterpret_cast<const bf16x8*>(
                qp + (size_t)(qbase + qg * 16 + l16) * D_ + ks * 32 + quad * 8);

    // staging geometry: lane -> (row ri, stored slot ci); logical chunk = ci^ri
    const int ri = lane >> 3;
    const int ci = lane & 7;
    const int gc = ci ^ ri;
    int koff[2], voff[2], lds_r[2];
#pragma unroll
    for (int g = 0; g < 2; ++g) {
        const int rb  = sub * 16 + g * 8;
        const int rho = rb + ri;
        const int pr  = (rho & 32) | ((rho & 12) << 1) | ((rho & 16) >> 2) | (rho & 3);
        koff[g]  = pr * D_ + gc * 8;          // K: permuted row, swizzled chunk
        voff[g]  = rho * N_ + gc * 8;         // V: linear d-row, swizzled chunk
        lds_r[g] = rb * 64;
    }

    f32x4 oacc[2][4];
    f32x4 lacc[2];
#pragma unroll
    for (int qg = 0; qg < 2; ++qg) {
        lacc[qg] = (f32x4){0, 0, 0, 0};
#pragma unroll
        for (int dt = 0; dt < 4; ++dt) oacc[qg][dt] = (f32x4){0, 0, 0, 0};
    }
    const f16x8 onesA = {1.f16, 1.f16, 1.f16, 1.f16, 1.f16, 1.f16, 1.f16, 1.f16};

    auto stage = [&](int buf, int t) {
        const int j0 = jh * 2048 + t * 64;
        short* kd = k_s + (size_t)(buf * 2 + jh) * 4096;
        f16*   vd = v_s + (size_t)(buf * 2 + jh) * 4096;
#pragma unroll
        for (int g = 0; g < 2; ++g) {
            load_lds16(kp + (size_t)j0 * D_ + koff[g], kd + lds_r[g]);
            load_lds16(vp + j0 + voff[g],              vd + lds_r[g]);
        }
    };

    stage(0, 0);
    __syncthreads();

    for (int t = 0; t < 32; ++t) {
        const int cur = t & 1;
        if (t < 31) stage(cur ^ 1, t + 1);    // DMA overlaps this tile's compute

        const short* kt  = k_s + (size_t)(cur * 2 + jh) * 4096;
        const f16*   vtl = v_s + (size_t)(cur * 2 + jh) * 4096;

        // S^T = K.Q^T (both q-groups share each K fragment)
        f32x4 s[2][4];
#pragma unroll
        for (int qg = 0; qg < 2; ++qg)
#pragma unroll
            for (int nt = 0; nt < 4; ++nt) s[qg][nt] = (f32x4){0, 0, 0, 0};
#pragma unroll
        for (int nt = 0; nt < 4; ++nt) {
            const int rb = (nt * 16 + l16) * 64;
            bf16x8 k0 = *reinterpret_cast<const bf16x8*>(kt + rb + ((quad    ) ^ l8) * 8);
            bf16x8 k1 = *reinterpret_cast<const bf16x8*>(kt + rb + ((4 + quad) ^ l8) * 8);
#pragma unroll
            for (int qg = 0; qg < 2; ++qg) {
                s[qg][nt] = __builtin_amdgcn_mfma_f32_16x16x32_bf16(k0, qb[qg][0], s[qg][nt], 0, 0, 0);
                s[qg][nt] = __builtin_amdgcn_mfma_f32_16x16x32_bf16(k1, qb[qg][1], s[qg][nt], 0, 0, 0);
            }
        }

        // p = exp2(s) -> f16 B-fragments in registers (pi makes order match V)
        f16x8 pb[2][2];
#pragma unroll
        for (int qg = 0; qg < 2; ++qg)
#pragma unroll
            for (int ks = 0; ks < 2; ++ks) {
                const f32x4 sa = s[qg][2 * ks], sb = s[qg][2 * ks + 1];
                u32x4 pw;
                pw.x = pkh2(EXP2(sa[0]), EXP2(sa[1]));
                pw.y = pkh2(EXP2(sa[2]), EXP2(sa[3]));
                pw.z = pkh2(EXP2(sb[0]), EXP2(sb[1]));
                pw.w = pkh2(EXP2(sb[2]), EXP2(sb[3]));
                pb[qg][ks] = __builtin_bit_cast(f16x8, pw);
                lacc[qg] = __builtin_amdgcn_mfma_f32_16x16x32_f16(onesA, pb[qg][ks], lacc[qg], 0, 0, 0);
            }

        // O^T += V^T . P^T
#pragma unroll
        for (int ks = 0; ks < 2; ++ks)
#pragma unroll
            for (int dt = 0; dt < 4; ++dt) {
                f16x8 va = *reinterpret_cast<const f16x8*>(
                    vtl + (dt * 16 + l16) * 64 + (((ks << 2) + quad) ^ l8) * 8);
#pragma unroll
                for (int qg = 0; qg < 2; ++qg)
                    oacc[qg][dt] = __builtin_amdgcn_mfma_f32_16x16x32_f16(va, pb[qg][ks], oacc[qg][dt], 0, 0, 0);
            }

        __syncthreads();   // drains this wave's DMA (t+1) + fences buf reads
    }

    // ---- merge j-halves (exact: O and l add) via lane-to-lane LDS slots ----
    float* mrg = reinterpret_cast<float*>(smem);   // staging buffers are dead
    const int slot = (sub * 64 + lane) * 35;       // odd stride: no conflicts
    if (jh == 1) {
#pragma unroll
        for (int qg = 0; qg < 2; ++qg) {
#pragma unroll
            for (int dt = 0; dt < 4; ++dt)
#pragma unroll
                for (int e = 0; e < 4; ++e)
                    mrg[slot + qg * 17 + dt * 4 + e] = oacc[qg][dt][e];
            mrg[slot + qg * 17 + 16] = lacc[qg][0];
        }
    }
    __syncthreads();
    if (jh == 0) {
#pragma unroll
        for (int qg = 0; qg < 2; ++qg) {
            const float rl = RCP(lacc[qg][0] + mrg[slot + qg * 17 + 16]);
            const size_t obase = ((size_t)bb * N_ + qbase + qg * 16 + l16) * C_ + h * D_;
#pragma unroll
            for (int dt = 0; dt < 4; ++dt) {
                float v0 = (oacc[qg][dt][0] + mrg[slot + qg * 17 + dt * 4 + 0]) * rl;
                float v1 = (oacc[qg][dt][1] + mrg[slot + qg * 17 + dt * 4 + 1]) * rl;
                float v2 = (oacc[qg][dt][2] + mrg[slot + qg * 17 + dt * 4 + 2]) * rl;
                float v3 = (oacc[qg][dt][3] + mrg[slot + qg * 17 + dt * 4 + 3]) * rl;
                u32x2 wv = { pk2(v0, v1), pk2(v2, v3) };
                *reinterpret_cast<u32x2*>(o + obase + dt * 16 + quad * 4) = wv;
            }
        }
    }
}

// ---------------------------------------------------------------------------
// Output projection, W staged in LDS. Swapped MFMA operands -> transposed
// accumulator -> f32x4 stores (4/lane) instead of 16 scalar f32 stores.
// ---------------------------------------------------------------------------
__global__ __launch_bounds__(256, 2) void out_proj_fast(const bf16* __restrict__ ov,
                                                        const bf16* __restrict__ w,
                                                        const float* __restrict__ bias,
                                                        float* __restrict__ out)
{
    __shared__ short w_s[64][264];
    const int tid  = threadIdx.x;
    const int lane = tid & 63;
    const int wav  = tid >> 6;
    const int quad = lane >> 4;
    const int l16  = lane & 15;
    const int bid = (blockIdx.x & 7) * 128 + (blockIdx.x >> 3);   // 1024 = 8*128
    const int m0 = (bid >> 2) * 64;
    const int n0 = (bid & 3) * 64;

    {
        const int row = tid >> 2, cb = (tid & 3) * 64;
        const bf16* src = w + (size_t)(n0 + row) * C_ + cb;
#pragma unroll
        for (int i = 0; i < 8; ++i)
            *reinterpret_cast<bf16x8*>(&w_s[row][cb + i * 8]) =
                *reinterpret_cast<const bf16x8*>(src + i * 8);
    }
    __syncthreads();

    f32x4 acc[4] = {{0,0,0,0},{0,0,0,0},{0,0,0,0},{0,0,0,0}};
    const bf16* orow = ov + (size_t)(m0 + wav * 16 + l16) * C_ + quad * 8;
#pragma unroll
    for (int k0 = 0; k0 < C_; k0 += 32) {
        bf16x8 a = *reinterpret_cast<const bf16x8*>(orow + k0);
#pragma unroll
        for (int nt = 0; nt < 4; ++nt) {
            bf16x8 b = *reinterpret_cast<const bf16x8*>(&w_s[nt * 16 + l16][k0 + quad * 8]);
            acc[nt] = __builtin_amdgcn_mfma_f32_16x16x32_bf16(b, a, acc[nt], 0, 0, 0);
        }
    }
    const int m = m0 + wav * 16 + l16;
#pragma unroll
    for (int nt = 0; nt < 4; ++nt) {
        const int oc0 = n0 + nt * 16 + quad * 4;
        f32x4 bv = *reinterpret_cast<const f32x4*>(bias + oc0);
        f32x4 ovv = acc[nt] + bv;
        *reinterpret_cast<f32x4*>(out + (size_t)m * C_ + oc0) = ovv;
    }
}

// Fallback: fp32 W with per-fragment cvt.
__global__ __launch_bounds__(256) void out_proj_cvt(const bf16* __restrict__ ov,
                                                    const float* __restrict__ w,
                                                    const float* __restrict__ bias,
                                                    float* __restrict__ out)
{
    const int lane = threadIdx.x & 63;
    const int wav  = threadIdx.x >> 6;
    const int quad = lane >> 4;
    const int l16  = lane & 15;
    const int gw   = blockIdx.x * 4 + wav;
    const int m0   = (gw >> 2) * 16;
    const int n0   = (gw & 3) * 64;

    f32x4 acc[4] = {{0,0,0,0},{0,0,0,0},{0,0,0,0},{0,0,0,0}};
    const bf16* orow = ov + (size_t)(m0 + l16) * C_ + quad * 8;
#pragma unroll
    for (int k0 = 0; k0 < C_; k0 += 32) {
        bf16x8 a = *reinterpret_cast<const bf16x8*>(orow + k0);
#pragma unroll
        for (int nt = 0; nt < 4; ++nt) {
            bf16x8 b = cvt8(w + (size_t)(n0 + nt * 16 + l16) * C_ + k0 + quad * 8);
            acc[nt] = __builtin_amdgcn_mfma_f32_16x16x32_bf16(a, b, acc[nt], 0, 0, 0);
        }
    }
#pragma unroll
    for (int nt = 0; nt < 4; ++nt)
#pragma unroll
        for (int r = 0; r < 4; ++r) {
            int m  = m0 + quad * 4 + r;
            int oc = n0 + nt * 16 + l16;
            out[(size_t)m * C_ + oc] = acc[nt][r] + bias[oc];
        }
}

extern "C" void kernel_launch(void* const* d_in, const int* in_sizes, int n_in,
                              void* d_out, int out_size, void* d_ws, size_t ws_size,
                              hipStream_t stream) {
    const float* x      = (const float*)d_in[0];
    const float* w_qkv  = (const float*)d_in[1];
    const float* w_proj = (const float*)d_in[2];
    const float* b_proj = (const float*)d_in[3];
    float* out = (float*)d_out;

    const size_t qkv_elems = (size_t)B_ * H_ * N_ * D_;   // 4,194,304
    bf16* q_ws  = (bf16*)d_ws;
    bf16* k_ws  = q_ws  + qkv_elems;
    f16*  vt_ws = (f16*)(k_ws + qkv_elems);
    bf16* o_ws  = (bf16*)(vt_ws + qkv_elems);
    bf16* x_bf  = o_ws  + qkv_elems;
    bf16* wq_bf = x_bf  + (size_t)B_ * N_ * C_;
    bf16* wp_bf = wq_bf + (size_t)3 * C_ * C_;

    const size_t need = ((size_t)4 * qkv_elems + (size_t)B_ * N_ * C_
                         + (size_t)3 * C_ * C_ + (size_t)C_ * C_) * 2;

    if (ws_size >= need) {
        cast_bf16    <<<2176, 256, 0, stream>>>(x, w_qkv, w_proj, x_bf, wq_bf, wp_bf);
        qkv_fast     <<<3072, 256, 0, stream>>>(x_bf, wq_bf, q_ws, k_ws, vt_ws);
        attn         <<< 512, 512, 0, stream>>>(q_ws, k_ws, vt_ws, o_ws);
        out_proj_fast<<<1024, 256, 0, stream>>>(o_ws, wp_bf, b_proj, out);
    } else {
        qkv_cvt      <<<3072, 256, 0, stream>>>(x, w_qkv, q_ws, k_ws, vt_ws);
        attn         <<< 512, 512, 0, stream>>>(q_ws, k_ws, vt_ws, o_ws);
        out_proj_cvt <<<1024, 256, 0, stream>>>(o_ws, w_proj, b_proj, out);
    }
}

// Round 2
// 174.932 us; speedup vs baseline: 1.0733x; 1.0401x over previous
//
#include <hip/hip_runtime.h>
#include <hip/hip_bf16.h>

typedef __hip_bfloat16 bf16;
typedef _Float16 f16;
typedef __attribute__((ext_vector_type(8))) short bf16x8;
typedef __attribute__((ext_vector_type(8))) _Float16 f16x8;
typedef __attribute__((ext_vector_type(2))) _Float16 f16x2;
typedef __attribute__((ext_vector_type(4))) float f32x4;
typedef __attribute__((ext_vector_type(4))) unsigned int u32x4;
typedef __attribute__((ext_vector_type(2))) unsigned int u32x2;

#define B_ 4
#define N_ 4096
#define C_ 256
#define H_ 4
#define D_ 64
#define KLN 0.18033688011112042f   /* 0.125 * log2(e): folded into Q */

#if __has_builtin(__builtin_amdgcn_exp2f)
#define EXP2(x) __builtin_amdgcn_exp2f(x)
#else
#define EXP2(x) exp2f(x)
#endif
#if __has_builtin(__builtin_amdgcn_rcpf)
#define RCP(x) __builtin_amdgcn_rcpf(x)
#else
#define RCP(x) (1.0f / (x))
#endif

// direct global->LDS DMA, 16B per lane. LDS dest = wave-uniform base + lane*16.
__device__ inline void load_lds16(const void* g, void* l) {
#if __has_builtin(__builtin_amdgcn_global_load_lds)
    __builtin_amdgcn_global_load_lds(
        (const __attribute__((address_space(1))) unsigned int*)g,
        (__attribute__((address_space(3))) unsigned int*)l, 16, 0, 0);
#else
    int ln = __lane_id();
    ((u32x4*)l)[ln] = *((const u32x4*)g);   // fallback (not used on gfx950)
#endif
}

// two fp32 -> packed bf16 pair (round-half-up)
__device__ inline unsigned int pk2(float a, float b) {
    unsigned int ua = __builtin_bit_cast(unsigned int, a) + 0x8000u;
    unsigned int ub = __builtin_bit_cast(unsigned int, b) + 0x8000u;
    return (ua >> 16) | (ub & 0xffff0000u);
}
// two fp32 -> packed f16 pair (single v_cvt_pkrtz_f16_f32)
__device__ inline unsigned int pkh2(float a, float b) {
#if __has_builtin(__builtin_amdgcn_cvt_pkrtz)
    return __builtin_bit_cast(unsigned int, __builtin_amdgcn_cvt_pkrtz(a, b));
#else
    f16x2 h = { (f16)a, (f16)b };
    return __builtin_bit_cast(unsigned int, h);
#endif
}
__device__ inline short f2s(float x) {
    return (short)__builtin_bit_cast(unsigned short, __float2bfloat16(x));
}
__device__ inline bf16x8 cvt8(const float* __restrict__ p) {
    f32x4 a = *reinterpret_cast<const f32x4*>(p);
    f32x4 b = *reinterpret_cast<const f32x4*>(p + 4);
    bf16x8 r = { f2s(a[0]), f2s(a[1]), f2s(a[2]), f2s(a[3]),
                 f2s(b[0]), f2s(b[1]), f2s(b[2]), f2s(b[3]) };
    return r;
}

// ---------------------------------------------------------------------------
// Prep: cast x, w_qkv, w_proj fp32 -> bf16 (memory-bound).
// ---------------------------------------------------------------------------
__global__ __launch_bounds__(256) void cast_bf16(const float* __restrict__ x,
                                                 const float* __restrict__ wq,
                                                 const float* __restrict__ wp,
                                                 bf16* __restrict__ xb,
                                                 bf16* __restrict__ wqb,
                                                 bf16* __restrict__ wpb)
{
    int bid = blockIdx.x;
    const float* s; bf16* d; int base;
    if (bid < 2048)      { s = x;  d = xb;  base = bid * 2048; }
    else if (bid < 2144) { s = wq; d = wqb; base = (bid - 2048) * 2048; }
    else                 { s = wp; d = wpb; base = (bid - 2144) * 2048; }
    int i = base + threadIdx.x * 8;
    f32x4 a = *reinterpret_cast<const f32x4*>(s + i);
    f32x4 b = *reinterpret_cast<const f32x4*>(s + i + 4);
    u32x4 o;
    o.x = pk2(a[0], a[1]); o.y = pk2(a[2], a[3]);
    o.z = pk2(b[0], b[1]); o.w = pk2(b[2], b[3]);
    *reinterpret_cast<u32x4*>(d + i) = o;
}

// ---------------------------------------------------------------------------
// QKV projection, W staged in LDS (once per 128-row m-tile: 2x amortized vs
// the 64-row version). Q pre-scaled by KLN; V -> [B,H,D,N] f16.
// Q/K use swapped MFMA operands -> transposed accumulator -> u32x2 stores.
// XCD swizzle groups the 12 n-tiles of each x-tile on one XCD (L2 reuse).
// ---------------------------------------------------------------------------
__global__ __launch_bounds__(256, 2) void qkv_fast(const bf16* __restrict__ x,
                                                   const bf16* __restrict__ w,
                                                   bf16* __restrict__ qw,
                                                   bf16* __restrict__ kw,
                                                   f16* __restrict__ vtw)
{
    __shared__ short w_s[64][264];
    const int tid  = threadIdx.x;
    const int lane = tid & 63;
    const int wav  = tid >> 6;
    const int quad = lane >> 4;
    const int l16  = lane & 15;
    const int bid = (blockIdx.x & 7) * 192 + (blockIdx.x >> 3);   // 1536 = 8*192
    const int mt = bid / 12, nb = bid % 12;
    const int m0 = mt * 128, n0 = nb * 64;

    {
        const int row = tid >> 2, cb = (tid & 3) * 64;
        const bf16* src = w + (size_t)(n0 + row) * C_ + cb;
#pragma unroll
        for (int i = 0; i < 8; ++i)
            *reinterpret_cast<bf16x8*>(&w_s[row][cb + i * 8]) =
                *reinterpret_cast<const bf16x8*>(src + i * 8);
    }
    __syncthreads();

#pragma unroll
    for (int half = 0; half < 2; ++half) {
        const int mh = m0 + half * 64;
        f32x4 acc[4] = {{0,0,0,0},{0,0,0,0},{0,0,0,0},{0,0,0,0}};
        const bf16* xrow = x + (size_t)(mh + wav * 16 + l16) * C_ + quad * 8;
        if (nb < 8) {        // Q/K: transposed accumulator (swapped operands)
#pragma unroll
            for (int k0 = 0; k0 < C_; k0 += 32) {
                bf16x8 a = *reinterpret_cast<const bf16x8*>(xrow + k0);
#pragma unroll
                for (int nt = 0; nt < 4; ++nt) {
                    bf16x8 b = *reinterpret_cast<const bf16x8*>(&w_s[nt * 16 + l16][k0 + quad * 8]);
                    acc[nt] = __builtin_amdgcn_mfma_f32_16x16x32_bf16(b, a, acc[nt], 0, 0, 0);
                }
            }
        } else {             // V: normal orientation (store wants n-contiguous)
#pragma unroll
            for (int k0 = 0; k0 < C_; k0 += 32) {
                bf16x8 a = *reinterpret_cast<const bf16x8*>(xrow + k0);
#pragma unroll
                for (int nt = 0; nt < 4; ++nt) {
                    bf16x8 b = *reinterpret_cast<const bf16x8*>(&w_s[nt * 16 + l16][k0 + quad * 8]);
                    acc[nt] = __builtin_amdgcn_mfma_f32_16x16x32_bf16(a, b, acc[nt], 0, 0, 0);
                }
            }
        }

        const int bb = mh >> 12;
        const int nbase = (mh + wav * 16) & (N_ - 1);
        if (nb < 4) {                            // Q (scaled): row n = nbase+l16
            bf16* dst = qw + (((size_t)bb * H_ + nb) * N_ + nbase + l16) * D_;
#pragma unroll
            for (int nt = 0; nt < 4; ++nt) {
                u32x2 wv = { pk2(acc[nt][0] * KLN, acc[nt][1] * KLN),
                             pk2(acc[nt][2] * KLN, acc[nt][3] * KLN) };
                *reinterpret_cast<u32x2*>(dst + nt * 16 + quad * 4) = wv;
            }
        } else if (nb < 8) {                     // K
            bf16* dst = kw + (((size_t)bb * H_ + (nb - 4)) * N_ + nbase + l16) * D_;
#pragma unroll
            for (int nt = 0; nt < 4; ++nt) {
                u32x2 wv = { pk2(acc[nt][0], acc[nt][1]),
                             pk2(acc[nt][2], acc[nt][3]) };
                *reinterpret_cast<u32x2*>(dst + nt * 16 + quad * 4) = wv;
            }
        } else {                                 // V transposed, f16
            const int h = nb - 8;
#pragma unroll
            for (int nt = 0; nt < 4; ++nt) {
                int d = nt * 16 + l16;
                u32x2 wv;
                wv.x = pkh2(acc[nt][0], acc[nt][1]);
                wv.y = pkh2(acc[nt][2], acc[nt][3]);
                *reinterpret_cast<u32x2*>(
                    vtw + (((size_t)bb * H_ + h) * D_ + d) * N_ + nbase + quad * 4) = wv;
            }
        }
    }
}

// Fallback: fp32 in, cvt per fragment.
__global__ __launch_bounds__(256) void qkv_cvt(const float* __restrict__ x,
                                               const float* __restrict__ w,
                                               bf16* __restrict__ qw,
                                               bf16* __restrict__ kw,
                                               f16* __restrict__ vtw)
{
    const int lane = threadIdx.x & 63;
    const int wav  = threadIdx.x >> 6;
    const int quad = lane >> 4;
    const int l16  = lane & 15;
    const int gw   = blockIdx.x * 4 + wav;
    const int m0   = (gw / 12) * 16;
    const int n0   = (gw % 12) * 64;

    f32x4 acc[4] = {{0,0,0,0},{0,0,0,0},{0,0,0,0},{0,0,0,0}};
    const float* xrow = x + (size_t)(m0 + l16) * C_ + quad * 8;
#pragma unroll
    for (int k0 = 0; k0 < C_; k0 += 32) {
        bf16x8 a = cvt8(xrow + k0);
#pragma unroll
        for (int nt = 0; nt < 4; ++nt) {
            bf16x8 b = cvt8(w + (size_t)(n0 + nt * 16 + l16) * C_ + k0 + quad * 8);
            acc[nt] = __builtin_amdgcn_mfma_f32_16x16x32_bf16(a, b, acc[nt], 0, 0, 0);
        }
    }
#pragma unroll
    for (int nt = 0; nt < 4; ++nt)
#pragma unroll
        for (int r = 0; r < 4; ++r) {
            int m  = m0 + quad * 4 + r;
            int o  = n0 + nt * 16 + l16;
            int bb = m >> 12;
            int n  = m & (N_ - 1);
            if (o < 256) {
                int h = o >> 6, d = o & 63;
                qw[(((size_t)bb * H_ + h) * N_ + n) * D_ + d] =
                    __float2bfloat16(acc[nt][r] * KLN);
            } else if (o < 512) {
                int oo = o - 256; int h = oo >> 6, d = oo & 63;
                kw[(((size_t)bb * H_ + h) * N_ + n) * D_ + d] =
                    __float2bfloat16(acc[nt][r]);
            } else {
                int oo = o - 512; int h = oo >> 6, d = oo & 63;
                vtw[(((size_t)bb * H_ + h) * D_ + d) * N_ + n] = (f16)acc[nt][r];
            }
        }
}

// ---------------------------------------------------------------------------
// Flash attention v6. Same structure as v5 (512-thread blocks = 4 q-subtiles
// x 2 j-halves, in-register P via K-row permutation, double-buffered K/V,
// one barrier per tile), with three stall reducers:
//  - l accumulated in f32 on the VALU (exp2 outputs summed per-lane, one
//    shfl_xor quad-reduce at the end) -> the 4 ones-MFMAs/tile are gone
//    (-11% matrix-pipe work) and l is *more* accurate (pre-f16-rounding).
//  - S chains start from a literal zero C operand (no per-tile v_mov init).
//  - s_setprio(1) around the QK and PV MFMA clusters (T5; the per-tile
//    phase split gives the CU scheduler roles to arbitrate).
// ---------------------------------------------------------------------------
__global__ __launch_bounds__(512, 4) void attn(const bf16* __restrict__ q,
                                               const bf16* __restrict__ k,
                                               const f16* __restrict__ vt,
                                               bf16* __restrict__ o)
{
    __shared__ __align__(16) char smem[65536];
    short* k_s = reinterpret_cast<short*>(smem);            // [buf][jh][64*64]
    f16*   v_s = reinterpret_cast<f16*>(smem + 32768);      // [buf][jh][64*64]

    const int tid  = threadIdx.x;
    const int lane = tid & 63;
    const int wav  = tid >> 6;       // 0..7
    const int quad = lane >> 4;
    const int l16  = lane & 15;
    const int l8   = lane & 7;
    const int sub  = wav & 3;        // 32-row q-slice within the 128-row tile
    const int jh   = wav >> 2;       // j-half

    const int wg = (blockIdx.x & 7) * 64 + (blockIdx.x >> 3);  // XCD swizzle
    const int bh = wg >> 5;
    const int qt = wg & 31;
    const int bb = bh >> 2, h = bh & 3;

    const bf16* qp = q  + (size_t)bh * N_ * D_;
    const bf16* kp = k  + (size_t)bh * N_ * D_;
    const f16*  vp = vt + (size_t)bh * D_ * N_;

    const int qbase = qt * 128 + sub * 32;
    bf16x8 qb[2][2];
#pragma unroll
    for (int qg = 0; qg < 2; ++qg)
#pragma unroll
        for (int ks = 0; ks < 2; ++ks)
            qb[qg][ks] = *reinterpret_cast<const bf16x8*>(
                qp + (size_t)(qbase + qg * 16 + l16) * D_ + ks * 32 + quad * 8);

    // staging geometry: lane -> (row ri, stored slot ci); logical chunk = ci^ri
    const int ri = lane >> 3;
    const int ci = lane & 7;
    const int gc = ci ^ ri;
    int koff[2], voff[2], lds_r[2];
#pragma unroll
    for (int g = 0; g < 2; ++g) {
        const int rb  = sub * 16 + g * 8;
        const int rho = rb + ri;
        const int pr  = (rho & 32) | ((rho & 12) << 1) | ((rho & 16) >> 2) | (rho & 3);
        koff[g]  = pr * D_ + gc * 8;          // K: permuted row, swizzled chunk
        voff[g]  = rho * N_ + gc * 8;         // V: linear d-row, swizzled chunk
        lds_r[g] = rb * 64;
    }

    f32x4 oacc[2][4];
    f32x4 lv[2];                    // per-lane f32 l partials (this quad's j's)
#pragma unroll
    for (int qg = 0; qg < 2; ++qg) {
        lv[qg] = (f32x4){0, 0, 0, 0};
#pragma unroll
        for (int dt = 0; dt < 4; ++dt) oacc[qg][dt] = (f32x4){0, 0, 0, 0};
    }

    auto stage = [&](int buf, int t) {
        const int j0 = jh * 2048 + t * 64;
        short* kd = k_s + (size_t)(buf * 2 + jh) * 4096;
        f16*   vd = v_s + (size_t)(buf * 2 + jh) * 4096;
#pragma unroll
        for (int g = 0; g < 2; ++g) {
            load_lds16(kp + (size_t)j0 * D_ + koff[g], kd + lds_r[g]);
            load_lds16(vp + j0 + voff[g],              vd + lds_r[g]);
        }
    };

    stage(0, 0);
    __syncthreads();

    for (int t = 0; t < 32; ++t) {
        const int cur = t & 1;
        if (t < 31) stage(cur ^ 1, t + 1);    // DMA overlaps this tile's compute

        const short* kt  = k_s + (size_t)(cur * 2 + jh) * 4096;
        const f16*   vtl = v_s + (size_t)(cur * 2 + jh) * 4096;

        // S^T = K.Q^T (both q-groups share each K fragment); C starts at 0
        f32x4 s[2][4];
        __builtin_amdgcn_s_setprio(1);
#pragma unroll
        for (int nt = 0; nt < 4; ++nt) {
            const int rb = (nt * 16 + l16) * 64;
            bf16x8 k0 = *reinterpret_cast<const bf16x8*>(kt + rb + ((quad    ) ^ l8) * 8);
            bf16x8 k1 = *reinterpret_cast<const bf16x8*>(kt + rb + ((4 + quad) ^ l8) * 8);
#pragma unroll
            for (int qg = 0; qg < 2; ++qg) {
                s[qg][nt] = __builtin_amdgcn_mfma_f32_16x16x32_bf16(
                    k0, qb[qg][0], (f32x4){0.f, 0.f, 0.f, 0.f}, 0, 0, 0);
                s[qg][nt] = __builtin_amdgcn_mfma_f32_16x16x32_bf16(
                    k1, qb[qg][1], s[qg][nt], 0, 0, 0);
            }
        }
        __builtin_amdgcn_s_setprio(0);

        // p = exp2(s) -> f16 B-fragments in registers; l += p on the VALU
        f16x8 pb[2][2];
#pragma unroll
        for (int qg = 0; qg < 2; ++qg)
#pragma unroll
            for (int ks = 0; ks < 2; ++ks) {
                const f32x4 sa = s[qg][2 * ks], sb = s[qg][2 * ks + 1];
                f32x4 pa = { EXP2(sa[0]), EXP2(sa[1]), EXP2(sa[2]), EXP2(sa[3]) };
                f32x4 pc = { EXP2(sb[0]), EXP2(sb[1]), EXP2(sb[2]), EXP2(sb[3]) };
                u32x4 pw;
                pw.x = pkh2(pa[0], pa[1]);
                pw.y = pkh2(pa[2], pa[3]);
                pw.z = pkh2(pc[0], pc[1]);
                pw.w = pkh2(pc[2], pc[3]);
                pb[qg][ks] = __builtin_bit_cast(f16x8, pw);
                lv[qg] += pa;
                lv[qg] += pc;
            }

        // O^T += V^T . P^T
        __builtin_amdgcn_s_setprio(1);
#pragma unroll
        for (int ks = 0; ks < 2; ++ks)
#pragma unroll
            for (int dt = 0; dt < 4; ++dt) {
                f16x8 va = *reinterpret_cast<const f16x8*>(
                    vtl + (dt * 16 + l16) * 64 + (((ks << 2) + quad) ^ l8) * 8);
#pragma unroll
                for (int qg = 0; qg < 2; ++qg)
                    oacc[qg][dt] = __builtin_amdgcn_mfma_f32_16x16x32_f16(va, pb[qg][ks], oacc[qg][dt], 0, 0, 0);
            }
        __builtin_amdgcn_s_setprio(0);

        __syncthreads();   // drains this wave's DMA (t+1) + fences buf reads
    }

    // l: horizontal sum + butterfly across the 4 quads (same l16 = same q-row)
    float lr[2];
#pragma unroll
    for (int qg = 0; qg < 2; ++qg) {
        float l = (lv[qg][0] + lv[qg][1]) + (lv[qg][2] + lv[qg][3]);
        l += __shfl_xor(l, 16);
        l += __shfl_xor(l, 32);
        lr[qg] = l;
    }

    // ---- merge j-halves (exact: O and l add) via lane-to-lane LDS slots ----
    float* mrg = reinterpret_cast<float*>(smem);   // staging buffers are dead
    const int slot = (sub * 64 + lane) * 35;       // odd stride: no conflicts
    if (jh == 1) {
#pragma unroll
        for (int qg = 0; qg < 2; ++qg) {
#pragma unroll
            for (int dt = 0; dt < 4; ++dt)
#pragma unroll
                for (int e = 0; e < 4; ++e)
                    mrg[slot + qg * 17 + dt * 4 + e] = oacc[qg][dt][e];
            mrg[slot + qg * 17 + 16] = lr[qg];
        }
    }
    __syncthreads();
    if (jh == 0) {
#pragma unroll
        for (int qg = 0; qg < 2; ++qg) {
            const float rl = RCP(lr[qg] + mrg[slot + qg * 17 + 16]);
            const size_t obase = ((size_t)bb * N_ + qbase + qg * 16 + l16) * C_ + h * D_;
#pragma unroll
            for (int dt = 0; dt < 4; ++dt) {
                float v0 = (oacc[qg][dt][0] + mrg[slot + qg * 17 + dt * 4 + 0]) * rl;
                float v1 = (oacc[qg][dt][1] + mrg[slot + qg * 17 + dt * 4 + 1]) * rl;
                float v2 = (oacc[qg][dt][2] + mrg[slot + qg * 17 + dt * 4 + 2]) * rl;
                float v3 = (oacc[qg][dt][3] + mrg[slot + qg * 17 + dt * 4 + 3]) * rl;
                u32x2 wv = { pk2(v0, v1), pk2(v2, v3) };
                *reinterpret_cast<u32x2*>(o + obase + dt * 16 + quad * 4) = wv;
            }
        }
    }
}

// ---------------------------------------------------------------------------
// Output projection, W staged in LDS once per 128-row m-tile. Swapped MFMA
// operands -> transposed accumulator -> f32x4 stores.
// ---------------------------------------------------------------------------
__global__ __launch_bounds__(256, 2) void out_proj_fast(const bf16* __restrict__ ov,
                                                        const bf16* __restrict__ w,
                                                        const float* __restrict__ bias,
                                                        float* __restrict__ out)
{
    __shared__ short w_s[64][264];
    const int tid  = threadIdx.x;
    const int lane = tid & 63;
    const int wav  = tid >> 6;
    const int quad = lane >> 4;
    const int l16  = lane & 15;
    const int bid = (blockIdx.x & 7) * 64 + (blockIdx.x >> 3);   // 512 = 8*64
    const int m0 = (bid >> 2) * 128;
    const int n0 = (bid & 3) * 64;

    {
        const int row = tid >> 2, cb = (tid & 3) * 64;
        const bf16* src = w + (size_t)(n0 + row) * C_ + cb;
#pragma unroll
        for (int i = 0; i < 8; ++i)
            *reinterpret_cast<bf16x8*>(&w_s[row][cb + i * 8]) =
                *reinterpret_cast<const bf16x8*>(src + i * 8);
    }
    __syncthreads();

#pragma unroll
    for (int half = 0; half < 2; ++half) {
        const int mh = m0 + half * 64;
        f32x4 acc[4] = {{0,0,0,0},{0,0,0,0},{0,0,0,0},{0,0,0,0}};
        const bf16* orow = ov + (size_t)(mh + wav * 16 + l16) * C_ + quad * 8;
#pragma unroll
        for (int k0 = 0; k0 < C_; k0 += 32) {
            bf16x8 a = *reinterpret_cast<const bf16x8*>(orow + k0);
#pragma unroll
            for (int nt = 0; nt < 4; ++nt) {
                bf16x8 b = *reinterpret_cast<const bf16x8*>(&w_s[nt * 16 + l16][k0 + quad * 8]);
                acc[nt] = __builtin_amdgcn_mfma_f32_16x16x32_bf16(b, a, acc[nt], 0, 0, 0);
            }
        }
        const int m = mh + wav * 16 + l16;
#pragma unroll
        for (int nt = 0; nt < 4; ++nt) {
            const int oc0 = n0 + nt * 16 + quad * 4;
            f32x4 bv = *reinterpret_cast<const f32x4*>(bias + oc0);
            f32x4 ovv = acc[nt] + bv;
            *reinterpret_cast<f32x4*>(out + (size_t)m * C_ + oc0) = ovv;
        }
    }
}

// Fallback: fp32 W with per-fragment cvt.
__global__ __launch_bounds__(256) void out_proj_cvt(const bf16* __restrict__ ov,
                                                    const float* __restrict__ w,
                                                    const float* __restrict__ bias,
                                                    float* __restrict__ out)
{
    const int lane = threadIdx.x & 63;
    const int wav  = threadIdx.x >> 6;
    const int quad = lane >> 4;
    const int l16  = lane & 15;
    const int gw   = blockIdx.x * 4 + wav;
    const int m0   = (gw >> 2) * 16;
    const int n0   = (gw & 3) * 64;

    f32x4 acc[4] = {{0,0,0,0},{0,0,0,0},{0,0,0,0},{0,0,0,0}};
    const bf16* orow = ov + (size_t)(m0 + l16) * C_ + quad * 8;
#pragma unroll
    for (int k0 = 0; k0 < C_; k0 += 32) {
        bf16x8 a = *reinterpret_cast<const bf16x8*>(orow + k0);
#pragma unroll
        for (int nt = 0; nt < 4; ++nt) {
            bf16x8 b = cvt8(w + (size_t)(n0 + nt * 16 + l16) * C_ + k0 + quad * 8);
            acc[nt] = __builtin_amdgcn_mfma_f32_16x16x32_bf16(a, b, acc[nt], 0, 0, 0);
        }
    }
#pragma unroll
    for (int nt = 0; nt < 4; ++nt)
#pragma unroll
        for (int r = 0; r < 4; ++r) {
            int m  = m0 + quad * 4 + r;
            int oc = n0 + nt * 16 + l16;
            out[(size_t)m * C_ + oc] = acc[nt][r] + bias[oc];
        }
}

extern "C" void kernel_launch(void* const* d_in, const int* in_sizes, int n_in,
                              void* d_out, int out_size, void* d_ws, size_t ws_size,
                              hipStream_t stream) {
    const float* x      = (const float*)d_in[0];
    const float* w_qkv  = (const float*)d_in[1];
    const float* w_proj = (const float*)d_in[2];
    const float* b_proj = (const float*)d_in[3];
    float* out = (float*)d_out;

    const size_t qkv_elems = (size_t)B_ * H_ * N_ * D_;   // 4,194,304
    bf16* q_ws  = (bf16*)d_ws;
    bf16* k_ws  = q_ws  + qkv_elems;
    f16*  vt_ws = (f16*)(k_ws + qkv_elems);
    bf16* o_ws  = (bf16*)(vt_ws + qkv_elems);
    bf16* x_bf  = o_ws  + qkv_elems;
    bf16* wq_bf = x_bf  + (size_t)B_ * N_ * C_;
    bf16* wp_bf = wq_bf + (size_t)3 * C_ * C_;

    const size_t need = ((size_t)4 * qkv_elems + (size_t)B_ * N_ * C_
                         + (size_t)3 * C_ * C_ + (size_t)C_ * C_) * 2;

    if (ws_size >= need) {
        cast_bf16    <<<2176, 256, 0, stream>>>(x, w_qkv, w_proj, x_bf, wq_bf, wp_bf);
        qkv_fast     <<<1536, 256, 0, stream>>>(x_bf, wq_bf, q_ws, k_ws, vt_ws);
        attn         <<< 512, 512, 0, stream>>>(q_ws, k_ws, vt_ws, o_ws);
        out_proj_fast<<< 512, 256, 0, stream>>>(o_ws, wp_bf, b_proj, out);
    } else {
        qkv_cvt      <<<3072, 256, 0, stream>>>(x, w_qkv, q_ws, k_ws, vt_ws);
        attn         <<< 512, 512, 0, stream>>>(q_ws, k_ws, vt_ws, o_ws);
        out_proj_cvt <<<1024, 256, 0, stream>>>(o_ws, w_proj, b_proj, out);
    }
}

// Round 3
// 174.804 us; speedup vs baseline: 1.0741x; 1.0007x over previous
//
#include <hip/hip_runtime.h>
#include <hip/hip_bf16.h>

typedef __hip_bfloat16 bf16;
typedef _Float16 f16;
typedef __attribute__((ext_vector_type(8))) short bf16x8;
typedef __attribute__((ext_vector_type(8))) _Float16 f16x8;
typedef __attribute__((ext_vector_type(2))) _Float16 f16x2;
typedef __attribute__((ext_vector_type(4))) float f32x4;
typedef __attribute__((ext_vector_type(4))) unsigned int u32x4;
typedef __attribute__((ext_vector_type(2))) unsigned int u32x2;

#define B_ 4
#define N_ 4096
#define C_ 256
#define H_ 4
#define D_ 64
#define KLN 0.18033688011112042f   /* 0.125 * log2(e): folded into Q */

#if __has_builtin(__builtin_amdgcn_exp2f)
#define EXP2(x) __builtin_amdgcn_exp2f(x)
#else
#define EXP2(x) exp2f(x)
#endif
#if __has_builtin(__builtin_amdgcn_rcpf)
#define RCP(x) __builtin_amdgcn_rcpf(x)
#else
#define RCP(x) (1.0f / (x))
#endif

// direct global->LDS DMA, 16B per lane. LDS dest = wave-uniform base + lane*16.
__device__ inline void load_lds16(const void* g, void* l) {
#if __has_builtin(__builtin_amdgcn_global_load_lds)
    __builtin_amdgcn_global_load_lds(
        (const __attribute__((address_space(1))) unsigned int*)g,
        (__attribute__((address_space(3))) unsigned int*)l, 16, 0, 0);
#else
    int ln = __lane_id();
    ((u32x4*)l)[ln] = *((const u32x4*)g);   // fallback (not used on gfx950)
#endif
}

// two fp32 -> packed bf16 pair (round-half-up)
__device__ inline unsigned int pk2(float a, float b) {
    unsigned int ua = __builtin_bit_cast(unsigned int, a) + 0x8000u;
    unsigned int ub = __builtin_bit_cast(unsigned int, b) + 0x8000u;
    return (ua >> 16) | (ub & 0xffff0000u);
}
// two fp32 -> packed f16 pair (single v_cvt_pkrtz_f16_f32)
__device__ inline unsigned int pkh2(float a, float b) {
#if __has_builtin(__builtin_amdgcn_cvt_pkrtz)
    return __builtin_bit_cast(unsigned int, __builtin_amdgcn_cvt_pkrtz(a, b));
#else
    f16x2 h = { (f16)a, (f16)b };
    return __builtin_bit_cast(unsigned int, h);
#endif
}
__device__ inline short f2s(float x) {
    return (short)__builtin_bit_cast(unsigned short, __float2bfloat16(x));
}
__device__ inline bf16x8 cvt8(const float* __restrict__ p) {
    f32x4 a = *reinterpret_cast<const f32x4*>(p);
    f32x4 b = *reinterpret_cast<const f32x4*>(p + 4);
    bf16x8 r = { f2s(a[0]), f2s(a[1]), f2s(a[2]), f2s(a[3]),
                 f2s(b[0]), f2s(b[1]), f2s(b[2]), f2s(b[3]) };
    return r;
}

// ---------------------------------------------------------------------------
// Prep: cast x, w_qkv, w_proj fp32 -> bf16 (memory-bound).
// ---------------------------------------------------------------------------
__global__ __launch_bounds__(256) void cast_bf16(const float* __restrict__ x,
                                                 const float* __restrict__ wq,
                                                 const float* __restrict__ wp,
                                                 bf16* __restrict__ xb,
                                                 bf16* __restrict__ wqb,
                                                 bf16* __restrict__ wpb)
{
    int bid = blockIdx.x;
    const float* s; bf16* d; int base;
    if (bid < 2048)      { s = x;  d = xb;  base = bid * 2048; }
    else if (bid < 2144) { s = wq; d = wqb; base = (bid - 2048) * 2048; }
    else                 { s = wp; d = wpb; base = (bid - 2144) * 2048; }
    int i = base + threadIdx.x * 8;
    f32x4 a = *reinterpret_cast<const f32x4*>(s + i);
    f32x4 b = *reinterpret_cast<const f32x4*>(s + i + 4);
    u32x4 o;
    o.x = pk2(a[0], a[1]); o.y = pk2(a[2], a[3]);
    o.z = pk2(b[0], b[1]); o.w = pk2(b[2], b[3]);
    *reinterpret_cast<u32x4*>(d + i) = o;
}

// ---------------------------------------------------------------------------
// QKV projection, W staged in LDS (once per 128-row m-tile). Q pre-scaled by
// KLN; V -> [B,H,D,N] f16. Q/K use swapped MFMA operands -> transposed
// accumulator -> u32x2 stores. XCD swizzle groups same-m-tile blocks.
// ---------------------------------------------------------------------------
__global__ __launch_bounds__(256, 2) void qkv_fast(const bf16* __restrict__ x,
                                                   const bf16* __restrict__ w,
                                                   bf16* __restrict__ qw,
                                                   bf16* __restrict__ kw,
                                                   f16* __restrict__ vtw)
{
    __shared__ short w_s[64][264];
    const int tid  = threadIdx.x;
    const int lane = tid & 63;
    const int wav  = tid >> 6;
    const int quad = lane >> 4;
    const int l16  = lane & 15;
    const int bid = (blockIdx.x & 7) * 192 + (blockIdx.x >> 3);   // 1536 = 8*192
    const int mt = bid / 12, nb = bid % 12;
    const int m0 = mt * 128, n0 = nb * 64;

    {
        const int row = tid >> 2, cb = (tid & 3) * 64;
        const bf16* src = w + (size_t)(n0 + row) * C_ + cb;
#pragma unroll
        for (int i = 0; i < 8; ++i)
            *reinterpret_cast<bf16x8*>(&w_s[row][cb + i * 8]) =
                *reinterpret_cast<const bf16x8*>(src + i * 8);
    }
    __syncthreads();

#pragma unroll
    for (int half = 0; half < 2; ++half) {
        const int mh = m0 + half * 64;
        f32x4 acc[4] = {{0,0,0,0},{0,0,0,0},{0,0,0,0},{0,0,0,0}};
        const bf16* xrow = x + (size_t)(mh + wav * 16 + l16) * C_ + quad * 8;
        if (nb < 8) {        // Q/K: transposed accumulator (swapped operands)
#pragma unroll
            for (int k0 = 0; k0 < C_; k0 += 32) {
                bf16x8 a = *reinterpret_cast<const bf16x8*>(xrow + k0);
#pragma unroll
                for (int nt = 0; nt < 4; ++nt) {
                    bf16x8 b = *reinterpret_cast<const bf16x8*>(&w_s[nt * 16 + l16][k0 + quad * 8]);
                    acc[nt] = __builtin_amdgcn_mfma_f32_16x16x32_bf16(b, a, acc[nt], 0, 0, 0);
                }
            }
        } else {             // V: normal orientation (store wants n-contiguous)
#pragma unroll
            for (int k0 = 0; k0 < C_; k0 += 32) {
                bf16x8 a = *reinterpret_cast<const bf16x8*>(xrow + k0);
#pragma unroll
                for (int nt = 0; nt < 4; ++nt) {
                    bf16x8 b = *reinterpret_cast<const bf16x8*>(&w_s[nt * 16 + l16][k0 + quad * 8]);
                    acc[nt] = __builtin_amdgcn_mfma_f32_16x16x32_bf16(a, b, acc[nt], 0, 0, 0);
                }
            }
        }

        const int bb = mh >> 12;
        const int nbase = (mh + wav * 16) & (N_ - 1);
        if (nb < 4) {                            // Q (scaled): row n = nbase+l16
            bf16* dst = qw + (((size_t)bb * H_ + nb) * N_ + nbase + l16) * D_;
#pragma unroll
            for (int nt = 0; nt < 4; ++nt) {
                u32x2 wv = { pk2(acc[nt][0] * KLN, acc[nt][1] * KLN),
                             pk2(acc[nt][2] * KLN, acc[nt][3] * KLN) };
                *reinterpret_cast<u32x2*>(dst + nt * 16 + quad * 4) = wv;
            }
        } else if (nb < 8) {                     // K
            bf16* dst = kw + (((size_t)bb * H_ + (nb - 4)) * N_ + nbase + l16) * D_;
#pragma unroll
            for (int nt = 0; nt < 4; ++nt) {
                u32x2 wv = { pk2(acc[nt][0], acc[nt][1]),
                             pk2(acc[nt][2], acc[nt][3]) };
                *reinterpret_cast<u32x2*>(dst + nt * 16 + quad * 4) = wv;
            }
        } else {                                 // V transposed, f16
            const int h = nb - 8;
#pragma unroll
            for (int nt = 0; nt < 4; ++nt) {
                int d = nt * 16 + l16;
                u32x2 wv;
                wv.x = pkh2(acc[nt][0], acc[nt][1]);
                wv.y = pkh2(acc[nt][2], acc[nt][3]);
                *reinterpret_cast<u32x2*>(
                    vtw + (((size_t)bb * H_ + h) * D_ + d) * N_ + nbase + quad * 4) = wv;
            }
        }
    }
}

// Fallback: fp32 in, cvt per fragment.
__global__ __launch_bounds__(256) void qkv_cvt(const float* __restrict__ x,
                                               const float* __restrict__ w,
                                               bf16* __restrict__ qw,
                                               bf16* __restrict__ kw,
                                               f16* __restrict__ vtw)
{
    const int lane = threadIdx.x & 63;
    const int wav  = threadIdx.x >> 6;
    const int quad = lane >> 4;
    const int l16  = lane & 15;
    const int gw   = blockIdx.x * 4 + wav;
    const int m0   = (gw / 12) * 16;
    const int n0   = (gw % 12) * 64;

    f32x4 acc[4] = {{0,0,0,0},{0,0,0,0},{0,0,0,0},{0,0,0,0}};
    const float* xrow = x + (size_t)(m0 + l16) * C_ + quad * 8;
#pragma unroll
    for (int k0 = 0; k0 < C_; k0 += 32) {
        bf16x8 a = cvt8(xrow + k0);
#pragma unroll
        for (int nt = 0; nt < 4; ++nt) {
            bf16x8 b = cvt8(w + (size_t)(n0 + nt * 16 + l16) * C_ + k0 + quad * 8);
            acc[nt] = __builtin_amdgcn_mfma_f32_16x16x32_bf16(a, b, acc[nt], 0, 0, 0);
        }
    }
#pragma unroll
    for (int nt = 0; nt < 4; ++nt)
#pragma unroll
        for (int r = 0; r < 4; ++r) {
            int m  = m0 + quad * 4 + r;
            int o  = n0 + nt * 16 + l16;
            int bb = m >> 12;
            int n  = m & (N_ - 1);
            if (o < 256) {
                int h = o >> 6, d = o & 63;
                qw[(((size_t)bb * H_ + h) * N_ + n) * D_ + d] =
                    __float2bfloat16(acc[nt][r] * KLN);
            } else if (o < 512) {
                int oo = o - 256; int h = oo >> 6, d = oo & 63;
                kw[(((size_t)bb * H_ + h) * N_ + n) * D_ + d] =
                    __float2bfloat16(acc[nt][r]);
            } else {
                int oo = o - 512; int h = oo >> 6, d = oo & 63;
                vtw[(((size_t)bb * H_ + h) * D_ + d) * N_ + n] = (f16)acc[nt][r];
            }
        }
}

// ---------------------------------------------------------------------------
// Flash attention v7. 256-thread blocks = 4 waves = 2 q-subtiles (64 rows,
// FOUR MFMA q-groups each) x 2 j-halves; grid 512 = 2 blocks/CU; each SIMD
// hosts 2 waves from DIFFERENT blocks (barrier phases overlap across blocks).
//
// Why 4 q-groups: round-2 counters showed the LDS read pipe as the binding
// resource (16 ds_read_b128/wave-tile x 16 waves/CU x 32 tiles x 12cyc
// ~= 41us > 33us MFMA floor). K/V fragment reads are shared across q-groups,
// so 64 q-rows/wave feeds 64 MFMAs from the same 16 reads -> LDS read time
// halves (~20us) and MFMA becomes the limiting pipe again.
//
// Same in-register P machinery as v5/v6: K rows staged under bit-shuffle
// permutation pi so S^T output slots land in PV B-fragment k-slot order;
// P goes exp2 -> v_cvt_pkrtz -> MFMA operand without touching LDS.
// l accumulated in f32 on the VALU. K/V double-buffered, 1 barrier/tile.
// No setprio (round-2 A/B: lockstep waves -> it cost ~3us).
// ---------------------------------------------------------------------------
__global__ __launch_bounds__(256, 2) void attn(const bf16* __restrict__ q,
                                               const bf16* __restrict__ k,
                                               const f16* __restrict__ vt,
                                               bf16* __restrict__ o)
{
    __shared__ __align__(16) char smem[65536];
    short* k_s = reinterpret_cast<short*>(smem);            // [buf][jh][64*64]
    f16*   v_s = reinterpret_cast<f16*>(smem + 32768);      // [buf][jh][64*64]

    const int tid  = threadIdx.x;
    const int lane = tid & 63;
    const int wav  = tid >> 6;       // 0..3
    const int quad = lane >> 4;
    const int l16  = lane & 15;
    const int l8   = lane & 7;
    const int sub  = wav & 1;        // 64-row q-slice within the 128-row tile
    const int jh   = wav >> 1;       // j-half

    const int wg = (blockIdx.x & 7) * 64 + (blockIdx.x >> 3);  // XCD swizzle
    const int bh = wg >> 5;
    const int qt = wg & 31;
    const int bb = bh >> 2, h = bh & 3;

    const bf16* qp = q  + (size_t)bh * N_ * D_;
    const bf16* kp = k  + (size_t)bh * N_ * D_;
    const f16*  vp = vt + (size_t)bh * D_ * N_;

    const int qbase = qt * 128 + sub * 64;
    bf16x8 qb[4][2];
#pragma unroll
    for (int qg = 0; qg < 4; ++qg)
#pragma unroll
        for (int ks = 0; ks < 2; ++ks)
            qb[qg][ks] = *reinterpret_cast<const bf16x8*>(
                qp + (size_t)(qbase + qg * 16 + l16) * D_ + ks * 32 + quad * 8);

    // staging geometry: lane -> (row ri, stored slot ci); logical chunk = ci^ri
    const int ri = lane >> 3;
    const int ci = lane & 7;
    const int gc = ci ^ ri;
    int koff[4], voff[4], lds_r[4];
#pragma unroll
    for (int g = 0; g < 4; ++g) {
        const int rb  = sub * 32 + g * 8;
        const int rho = rb + ri;
        const int pr  = (rho & 32) | ((rho & 12) << 1) | ((rho & 16) >> 2) | (rho & 3);
        koff[g]  = pr * D_ + gc * 8;          // K: permuted row, swizzled chunk
        voff[g]  = rho * N_ + gc * 8;         // V: linear d-row, swizzled chunk
        lds_r[g] = rb * 64;
    }

    f32x4 oacc[4][4];
    f32x4 lv[4];                    // per-lane f32 l partials (this quad's j's)
#pragma unroll
    for (int qg = 0; qg < 4; ++qg) {
        lv[qg] = (f32x4){0, 0, 0, 0};
#pragma unroll
        for (int dt = 0; dt < 4; ++dt) oacc[qg][dt] = (f32x4){0, 0, 0, 0};
    }

    auto stage = [&](int buf, int t) {
        const int j0 = jh * 2048 + t * 64;
        short* kd = k_s + (size_t)(buf * 2 + jh) * 4096;
        f16*   vd = v_s + (size_t)(buf * 2 + jh) * 4096;
#pragma unroll
        for (int g = 0; g < 4; ++g) {
            load_lds16(kp + (size_t)j0 * D_ + koff[g], kd + lds_r[g]);
            load_lds16(vp + j0 + voff[g],              vd + lds_r[g]);
        }
    };

    stage(0, 0);
    __syncthreads();

    for (int t = 0; t < 32; ++t) {
        const int cur = t & 1;
        if (t < 31) stage(cur ^ 1, t + 1);    // DMA overlaps this tile's compute

        const short* kt  = k_s + (size_t)(cur * 2 + jh) * 4096;
        const f16*   vtl = v_s + (size_t)(cur * 2 + jh) * 4096;

        // S^T = K.Q^T (all 4 q-groups share each K fragment); C starts at 0
        f16x8 pb[4][2];
#pragma unroll
        for (int nt = 0; nt < 4; ++nt) {
            const int rb = (nt * 16 + l16) * 64;
            bf16x8 k0 = *reinterpret_cast<const bf16x8*>(kt + rb + ((quad    ) ^ l8) * 8);
            bf16x8 k1 = *reinterpret_cast<const bf16x8*>(kt + rb + ((4 + quad) ^ l8) * 8);
#pragma unroll
            for (int qg = 0; qg < 4; ++qg) {
                f32x4 sv = __builtin_amdgcn_mfma_f32_16x16x32_bf16(
                    k0, qb[qg][0], (f32x4){0.f, 0.f, 0.f, 0.f}, 0, 0, 0);
                sv = __builtin_amdgcn_mfma_f32_16x16x32_bf16(
                    k1, qb[qg][1], sv, 0, 0, 0);
                // p = exp2(s): half a P-fragment per (qg, nt); nt pairs form ks
                f32x4 pa = { EXP2(sv[0]), EXP2(sv[1]), EXP2(sv[2]), EXP2(sv[3]) };
                u32x2 pw = { pkh2(pa[0], pa[1]), pkh2(pa[2], pa[3]) };
                if (nt & 1)
                    *(reinterpret_cast<u32x2*>(&pb[qg][nt >> 1]) + 1) = pw;
                else
                    *(reinterpret_cast<u32x2*>(&pb[qg][nt >> 1]) + 0) = pw;
                lv[qg] += pa;
            }
        }

        // O^T += V^T . P^T
#pragma unroll
        for (int ks = 0; ks < 2; ++ks)
#pragma unroll
            for (int dt = 0; dt < 4; ++dt) {
                f16x8 va = *reinterpret_cast<const f16x8*>(
                    vtl + (dt * 16 + l16) * 64 + (((ks << 2) + quad) ^ l8) * 8);
#pragma unroll
                for (int qg = 0; qg < 4; ++qg)
                    oacc[qg][dt] = __builtin_amdgcn_mfma_f32_16x16x32_f16(va, pb[qg][ks], oacc[qg][dt], 0, 0, 0);
            }

        __syncthreads();   // drains this wave's DMA (t+1) + fences buf reads
    }

    // l: horizontal sum + butterfly across the 4 quads (same l16 = same q-row)
    float lr[4];
#pragma unroll
    for (int qg = 0; qg < 4; ++qg) {
        float l = (lv[qg][0] + lv[qg][1]) + (lv[qg][2] + lv[qg][3]);
        l += __shfl_xor(l, 16);
        l += __shfl_xor(l, 32);
        lr[qg] = l;
    }

    // ---- merge j-halves (exact: O and l add) via lane-to-lane LDS slots ----
    float* mrg = reinterpret_cast<float*>(smem);   // staging buffers are dead
    const int slot = (sub * 64 + lane) * 69;       // odd stride: no conflicts
    if (jh == 1) {
#pragma unroll
        for (int qg = 0; qg < 4; ++qg) {
#pragma unroll
            for (int dt = 0; dt < 4; ++dt)
#pragma unroll
                for (int e = 0; e < 4; ++e)
                    mrg[slot + qg * 17 + dt * 4 + e] = oacc[qg][dt][e];
            mrg[slot + qg * 17 + 16] = lr[qg];
        }
    }
    __syncthreads();
    if (jh == 0) {
#pragma unroll
        for (int qg = 0; qg < 4; ++qg) {
            const float rl = RCP(lr[qg] + mrg[slot + qg * 17 + 16]);
            const size_t obase = ((size_t)bb * N_ + qbase + qg * 16 + l16) * C_ + h * D_;
#pragma unroll
            for (int dt = 0; dt < 4; ++dt) {
                float v0 = (oacc[qg][dt][0] + mrg[slot + qg * 17 + dt * 4 + 0]) * rl;
                float v1 = (oacc[qg][dt][1] + mrg[slot + qg * 17 + dt * 4 + 1]) * rl;
                float v2 = (oacc[qg][dt][2] + mrg[slot + qg * 17 + dt * 4 + 2]) * rl;
                float v3 = (oacc[qg][dt][3] + mrg[slot + qg * 17 + dt * 4 + 3]) * rl;
                u32x2 wv = { pk2(v0, v1), pk2(v2, v3) };
                *reinterpret_cast<u32x2*>(o + obase + dt * 16 + quad * 4) = wv;
            }
        }
    }
}

// ---------------------------------------------------------------------------
// Output projection, W staged in LDS once per 128-row m-tile. Swapped MFMA
// operands -> transposed accumulator -> f32x4 stores.
// ---------------------------------------------------------------------------
__global__ __launch_bounds__(256, 2) void out_proj_fast(const bf16* __restrict__ ov,
                                                        const bf16* __restrict__ w,
                                                        const float* __restrict__ bias,
                                                        float* __restrict__ out)
{
    __shared__ short w_s[64][264];
    const int tid  = threadIdx.x;
    const int lane = tid & 63;
    const int wav  = tid >> 6;
    const int quad = lane >> 4;
    const int l16  = lane & 15;
    const int bid = (blockIdx.x & 7) * 64 + (blockIdx.x >> 3);   // 512 = 8*64
    const int m0 = (bid >> 2) * 128;
    const int n0 = (bid & 3) * 64;

    {
        const int row = tid >> 2, cb = (tid & 3) * 64;
        const bf16* src = w + (size_t)(n0 + row) * C_ + cb;
#pragma unroll
        for (int i = 0; i < 8; ++i)
            *reinterpret_cast<bf16x8*>(&w_s[row][cb + i * 8]) =
                *reinterpret_cast<const bf16x8*>(src + i * 8);
    }
    __syncthreads();

#pragma unroll
    for (int half = 0; half < 2; ++half) {
        const int mh = m0 + half * 64;
        f32x4 acc[4] = {{0,0,0,0},{0,0,0,0},{0,0,0,0},{0,0,0,0}};
        const bf16* orow = ov + (size_t)(mh + wav * 16 + l16) * C_ + quad * 8;
#pragma unroll
        for (int k0 = 0; k0 < C_; k0 += 32) {
            bf16x8 a = *reinterpret_cast<const bf16x8*>(orow + k0);
#pragma unroll
            for (int nt = 0; nt < 4; ++nt) {
                bf16x8 b = *reinterpret_cast<const bf16x8*>(&w_s[nt * 16 + l16][k0 + quad * 8]);
                acc[nt] = __builtin_amdgcn_mfma_f32_16x16x32_bf16(b, a, acc[nt], 0, 0, 0);
            }
        }
        const int m = mh + wav * 16 + l16;
#pragma unroll
        for (int nt = 0; nt < 4; ++nt) {
            const int oc0 = n0 + nt * 16 + quad * 4;
            f32x4 bv = *reinterpret_cast<const f32x4*>(bias + oc0);
            f32x4 ovv = acc[nt] + bv;
            *reinterpret_cast<f32x4*>(out + (size_t)m * C_ + oc0) = ovv;
        }
    }
}

// Fallback: fp32 W with per-fragment cvt.
__global__ __launch_bounds__(256) void out_proj_cvt(const bf16* __restrict__ ov,
                                                    const float* __restrict__ w,
                                                    const float* __restrict__ bias,
                                                    float* __restrict__ out)
{
    const int lane = threadIdx.x & 63;
    const int wav  = threadIdx.x >> 6;
    const int quad = lane >> 4;
    const int l16  = lane & 15;
    const int gw   = blockIdx.x * 4 + wav;
    const int m0   = (gw >> 2) * 16;
    const int n0   = (gw & 3) * 64;

    f32x4 acc[4] = {{0,0,0,0},{0,0,0,0},{0,0,0,0},{0,0,0,0}};
    const bf16* orow = ov + (size_t)(m0 + l16) * C_ + quad * 8;
#pragma unroll
    for (int k0 = 0; k0 < C_; k0 += 32) {
        bf16x8 a = *reinterpret_cast<const bf16x8*>(orow + k0);
#pragma unroll
        for (int nt = 0; nt < 4; ++nt) {
            bf16x8 b = cvt8(w + (size_t)(n0 + nt * 16 + l16) * C_ + k0 + quad * 8);
            acc[nt] = __builtin_amdgcn_mfma_f32_16x16x32_bf16(a, b, acc[nt], 0, 0, 0);
        }
    }
#pragma unroll
    for (int nt = 0; nt < 4; ++nt)
#pragma unroll
        for (int r = 0; r < 4; ++r) {
            int m  = m0 + quad * 4 + r;
            int oc = n0 + nt * 16 + l16;
            out[(size_t)m * C_ + oc] = acc[nt][r] + bias[oc];
        }
}

extern "C" void kernel_launch(void* const* d_in, const int* in_sizes, int n_in,
                              void* d_out, int out_size, void* d_ws, size_t ws_size,
                              hipStream_t stream) {
    const float* x      = (const float*)d_in[0];
    const float* w_qkv  = (const float*)d_in[1];
    const float* w_proj = (const float*)d_in[2];
    const float* b_proj = (const float*)d_in[3];
    float* out = (float*)d_out;

    const size_t qkv_elems = (size_t)B_ * H_ * N_ * D_;   // 4,194,304
    bf16* q_ws  = (bf16*)d_ws;
    bf16* k_ws  = q_ws  + qkv_elems;
    f16*  vt_ws = (f16*)(k_ws + qkv_elems);
    bf16* o_ws  = (bf16*)(vt_ws + qkv_elems);
    bf16* x_bf  = o_ws  + qkv_elems;
    bf16* wq_bf = x_bf  + (size_t)B_ * N_ * C_;
    bf16* wp_bf = wq_bf + (size_t)3 * C_ * C_;

    const size_t need = ((size_t)4 * qkv_elems + (size_t)B_ * N_ * C_
                         + (size_t)3 * C_ * C_ + (size_t)C_ * C_) * 2;

    if (ws_size >= need) {
        cast_bf16    <<<2176, 256, 0, stream>>>(x, w_qkv, w_proj, x_bf, wq_bf, wp_bf);
        qkv_fast     <<<1536, 256, 0, stream>>>(x_bf, wq_bf, q_ws, k_ws, vt_ws);
        attn         <<< 512, 256, 0, stream>>>(q_ws, k_ws, vt_ws, o_ws);
        out_proj_fast<<< 512, 256, 0, stream>>>(o_ws, wp_bf, b_proj, out);
    } else {
        qkv_cvt      <<<3072, 256, 0, stream>>>(x, w_qkv, q_ws, k_ws, vt_ws);
        attn         <<< 512, 256, 0, stream>>>(q_ws, k_ws, vt_ws, o_ws);
        out_proj_cvt <<<1024, 256, 0, stream>>>(o_ws, w_proj, b_proj, out);
    }
}